// Round 2
// baseline (177.095 us; speedup 1.0000x reference)
//
#include <hip/hip_runtime.h>

#define NTOK 16384
#define NC 2048
#define C4 512            // float4 per row
#define NE 8
#define TPB 512           // 8 waves
#define TOK_PER_BLOCK 32  // 8 waves x 4 tokens
#define NBLK (NTOK / TOK_PER_BLOCK)   // 512

__global__ void zero_ws_kernel(float* ws) {
    if (threadIdx.x < 2 * NE) ws[threadIdx.x] = 0.0f;
}

__global__ __launch_bounds__(TPB, 4) void router_kernel(
    const float* __restrict__ x, const float* __restrict__ gw,
    float* __restrict__ out, float* __restrict__ ws) {
    __shared__ float4 s_gw[NE * C4];   // 64 KB
    __shared__ float s_psum[NE];
    __shared__ float s_cnt[NE];

    const int tid = threadIdx.x;
    if (tid < NE) { s_psum[tid] = 0.0f; s_cnt[tid] = 0.0f; }

    // stage gate_w -> LDS (4096 float4, 8 per thread, coalesced)
    const float4* gw4 = (const float4*)gw;
    #pragma unroll
    for (int i = tid; i < NE * C4; i += TPB) s_gw[i] = gw4[i];
    __syncthreads();

    const int wave = tid >> 6;
    const int lane = tid & 63;
    const float4* x4 = (const float4*)x;
    const int t0 = blockIdx.x * TOK_PER_BLOCK + wave * 4;   // 4 tokens per wave

    float* out_w = out;               // weights [N,2]
    float* out_i = out + 2 * NTOK;    // indices [N,2] stored as float

    float acc[4][NE];
    #pragma unroll
    for (int t = 0; t < 4; ++t)
        #pragma unroll
        for (int e = 0; e < NE; ++e) acc[t][e] = 0.0f;

    #pragma unroll
    for (int k = 0; k < 8; ++k) {
        const int idx = lane + k * 64;
        float4 xv[4];
        #pragma unroll
        for (int t = 0; t < 4; ++t)
            xv[t] = x4[(size_t)(t0 + t) * C4 + idx];
        #pragma unroll
        for (int e = 0; e < NE; ++e) {
            const float4 wv = s_gw[e * C4 + idx];
            #pragma unroll
            for (int t = 0; t < 4; ++t) {
                acc[t][e] += xv[t].x * wv.x + xv[t].y * wv.y +
                             xv[t].z * wv.z + xv[t].w * wv.w;
            }
        }
    }

    // butterfly reduce over 64 lanes: every lane ends with full sums
    #pragma unroll
    for (int off = 32; off >= 1; off >>= 1) {
        #pragma unroll
        for (int t = 0; t < 4; ++t)
            #pragma unroll
            for (int e = 0; e < NE; ++e)
                acc[t][e] += __shfl_xor(acc[t][e], off, 64);
    }

    if (lane < 4) {
        const int t = lane;
        const int token = t0 + t;
        // static-index select (NO runtime indexing into register array!)
        float l[NE];
        #pragma unroll
        for (int e = 0; e < NE; ++e) {
            float v = acc[0][e];
            v = (t == 1) ? acc[1][e] : v;
            v = (t == 2) ? acc[2][e] : v;
            v = (t == 3) ? acc[3][e] : v;
            l[e] = v;
        }

        float m = l[0];
        #pragma unroll
        for (int e = 1; e < NE; ++e) m = fmaxf(m, l[e]);
        float p[NE];
        float s = 0.0f;
        #pragma unroll
        for (int e = 0; e < NE; ++e) { p[e] = expf(l[e] - m); s += p[e]; }
        const float inv = 1.0f / s;
        #pragma unroll
        for (int e = 0; e < NE; ++e) p[e] *= inv;

        // top-2 with ties -> lower index (matches jax.lax.top_k)
        int i0 = 0; float p0 = p[0];
        #pragma unroll
        for (int e = 1; e < NE; ++e) if (p[e] > p0) { p0 = p[e]; i0 = e; }
        int i1 = (i0 == 0) ? 1 : 0; float p1 = p[i1];
        #pragma unroll
        for (int e = 0; e < NE; ++e)
            if (e != i0 && p[e] > p1) { p1 = p[e]; i1 = e; }

        const float wsum = p0 + p1;
        out_w[2 * token]     = p0 / wsum;
        out_w[2 * token + 1] = p1 / wsum;
        out_i[2 * token]     = (float)i0;
        out_i[2 * token + 1] = (float)i1;

        #pragma unroll
        for (int e = 0; e < NE; ++e) atomicAdd(&s_psum[e], p[e]);
        atomicAdd(&s_cnt[i0], 1.0f);
        atomicAdd(&s_cnt[i1], 1.0f);
    }

    __syncthreads();
    if (tid < NE) {
        atomicAdd(&ws[tid], s_psum[tid]);
        atomicAdd(&ws[NE + tid], s_cnt[tid]);
    }
}

__global__ void finalize_kernel(const float* __restrict__ ws,
                                float* __restrict__ out) {
    float aux = 0.0f;
    #pragma unroll
    for (int e = 0; e < NE; ++e)
        aux += (ws[NE + e] * (1.0f / NTOK)) * (ws[e] * (1.0f / NTOK));
    out[4 * NTOK] = (float)NE * aux;
}

extern "C" void kernel_launch(void* const* d_in, const int* in_sizes, int n_in,
                              void* d_out, int out_size, void* d_ws, size_t ws_size,
                              hipStream_t stream) {
    const float* x  = (const float*)d_in[0];   // [4,4096,2048] f32
    const float* gw = (const float*)d_in[1];   // [8,2048] f32
    float* out = (float*)d_out;                // weights[N,2] | indices[N,2] | aux
    float* ws  = (float*)d_ws;                 // psum[8] | cnt[8]

    zero_ws_kernel<<<1, 64, 0, stream>>>(ws);
    router_kernel<<<NBLK, TPB, 0, stream>>>(x, gw, out, ws);
    finalize_kernel<<<1, 1, 0, stream>>>(ws, out);
}

// Round 3
// 170.146 us; speedup vs baseline: 1.0408x; 1.0408x over previous
//
#include <hip/hip_runtime.h>

#define NTOK 16384
#define NC 2048
#define C4 512            // float4 per row
#define NE 8
#define TPB 256           // 4 waves
#define TOK_PER_BLOCK 16  // 4 waves x 4 tokens
#define NBLK (NTOK / TOK_PER_BLOCK)   // 1024

__global__ void zero_ws_kernel(float* ws) {
    if (threadIdx.x < 2 * NE) ws[threadIdx.x] = 0.0f;
}

__global__ __launch_bounds__(TPB, 4) void router_kernel(
    const float* __restrict__ x, const float* __restrict__ gw,
    float* __restrict__ out, float* __restrict__ ws) {
    __shared__ float s_psum[NE];
    __shared__ float s_cnt[NE];

    const int tid = threadIdx.x;
    if (tid < NE) { s_psum[tid] = 0.0f; s_cnt[tid] = 0.0f; }
    __syncthreads();

    const int wave = tid >> 6;
    const int lane = tid & 63;
    const float4* x4 = (const float4*)x;
    const float4* gw4 = (const float4*)gw;
    const int t0 = blockIdx.x * TOK_PER_BLOCK + wave * 4;   // 4 tokens per wave

    float* out_w = out;               // weights [N,2]
    float* out_i = out + 2 * NTOK;    // indices [N,2] stored as float

    float acc[4][NE];
    #pragma unroll
    for (int t = 0; t < 4; ++t)
        #pragma unroll
        for (int e = 0; e < NE; ++e) acc[t][e] = 0.0f;

    #pragma unroll
    for (int k = 0; k < 8; ++k) {
        const int idx = lane + k * 64;
        float4 xv[4];
        #pragma unroll
        for (int t = 0; t < 4; ++t)
            xv[t] = x4[(size_t)(t0 + t) * C4 + idx];
        #pragma unroll
        for (int e = 0; e < NE; ++e) {
            const float4 wv = gw4[e * C4 + idx];   // same addrs every block -> L1/L2
            #pragma unroll
            for (int t = 0; t < 4; ++t) {
                acc[t][e] += xv[t].x * wv.x + xv[t].y * wv.y +
                             xv[t].z * wv.z + xv[t].w * wv.w;
            }
        }
    }

    // butterfly reduce over 64 lanes: every lane ends with full sums
    #pragma unroll
    for (int off = 32; off >= 1; off >>= 1) {
        #pragma unroll
        for (int t = 0; t < 4; ++t)
            #pragma unroll
            for (int e = 0; e < NE; ++e)
                acc[t][e] += __shfl_xor(acc[t][e], off, 64);
    }

    if (lane < 4) {
        const int t = lane;
        const int token = t0 + t;
        // static-index select (NO runtime indexing into register array!)
        float l[NE];
        #pragma unroll
        for (int e = 0; e < NE; ++e) {
            float v = acc[0][e];
            v = (t == 1) ? acc[1][e] : v;
            v = (t == 2) ? acc[2][e] : v;
            v = (t == 3) ? acc[3][e] : v;
            l[e] = v;
        }

        float m = l[0];
        #pragma unroll
        for (int e = 1; e < NE; ++e) m = fmaxf(m, l[e]);
        float p[NE];
        float s = 0.0f;
        #pragma unroll
        for (int e = 0; e < NE; ++e) { p[e] = expf(l[e] - m); s += p[e]; }
        const float inv = 1.0f / s;
        #pragma unroll
        for (int e = 0; e < NE; ++e) p[e] *= inv;

        // top-2 with ties -> lower index (matches jax.lax.top_k)
        int i0 = 0; float p0 = p[0];
        #pragma unroll
        for (int e = 1; e < NE; ++e) if (p[e] > p0) { p0 = p[e]; i0 = e; }
        int i1 = (i0 == 0) ? 1 : 0; float p1 = p[i1];
        #pragma unroll
        for (int e = 0; e < NE; ++e)
            if (e != i0 && p[e] > p1) { p1 = p[e]; i1 = e; }

        const float wsum = p0 + p1;
        out_w[2 * token]     = p0 / wsum;
        out_w[2 * token + 1] = p1 / wsum;
        out_i[2 * token]     = (float)i0;
        out_i[2 * token + 1] = (float)i1;

        #pragma unroll
        for (int e = 0; e < NE; ++e) atomicAdd(&s_psum[e], p[e]);
        atomicAdd(&s_cnt[i0], 1.0f);
        atomicAdd(&s_cnt[i1], 1.0f);
    }

    __syncthreads();
    if (tid < NE) {
        atomicAdd(&ws[tid], s_psum[tid]);
        atomicAdd(&ws[NE + tid], s_cnt[tid]);
    }
}

__global__ void finalize_kernel(const float* __restrict__ ws,
                                float* __restrict__ out) {
    float aux = 0.0f;
    #pragma unroll
    for (int e = 0; e < NE; ++e)
        aux += (ws[NE + e] * (1.0f / NTOK)) * (ws[e] * (1.0f / NTOK));
    out[4 * NTOK] = (float)NE * aux;
}

extern "C" void kernel_launch(void* const* d_in, const int* in_sizes, int n_in,
                              void* d_out, int out_size, void* d_ws, size_t ws_size,
                              hipStream_t stream) {
    const float* x  = (const float*)d_in[0];   // [4,4096,2048] f32
    const float* gw = (const float*)d_in[1];   // [8,2048] f32
    float* out = (float*)d_out;                // weights[N,2] | indices[N,2] | aux
    float* ws  = (float*)d_ws;                 // psum[8] | cnt[8]

    zero_ws_kernel<<<1, 64, 0, stream>>>(ws);
    router_kernel<<<NBLK, TPB, 0, stream>>>(x, gw, out, ws);
    finalize_kernel<<<1, 1, 0, stream>>>(ws, out);
}

// Round 4
// 83.580 us; speedup vs baseline: 2.1189x; 2.0357x over previous
//
#include <hip/hip_runtime.h>

#define NTOK 16384
#define NC 2048
#define C4 512            // float4 per row
#define NE 8
#define TPB 256           // 4 waves
#define TOK_PER_BLOCK 16  // 4 waves x 4 tokens
#define NBLK (NTOK / TOK_PER_BLOCK)   // 1024

__global__ void zero_ws_kernel(float* ws) {
    if (threadIdx.x < 2 * NE) ws[threadIdx.x] = 0.0f;
}

// NOTE: hipcc VGPR cap behaves as ~256/min_waves arg:
//   (256,2) -> 128 VGPRs (fits ~100-reg working set, no spill)
//   (256,4) -> 64 VGPRs  (spills acc[] -> 289MB scratch traffic, R3)
__global__ __launch_bounds__(TPB, 2) void router_kernel(
    const float* __restrict__ x, const float* __restrict__ gw,
    float* __restrict__ out, float* __restrict__ ws) {
    __shared__ float s_psum[NE];
    __shared__ float s_cnt[NE];

    const int tid = threadIdx.x;
    if (tid < NE) { s_psum[tid] = 0.0f; s_cnt[tid] = 0.0f; }
    __syncthreads();

    const int wave = tid >> 6;
    const int lane = tid & 63;
    const float4* x4 = (const float4*)x;
    const float4* gw4 = (const float4*)gw;
    const int t0 = blockIdx.x * TOK_PER_BLOCK + wave * 4;   // 4 tokens per wave

    float* out_w = out;               // weights [N,2]
    float* out_i = out + 2 * NTOK;    // indices [N,2] stored as float

    float acc[4][NE];
    #pragma unroll
    for (int t = 0; t < 4; ++t)
        #pragma unroll
        for (int e = 0; e < NE; ++e) acc[t][e] = 0.0f;

    #pragma unroll
    for (int k = 0; k < 8; ++k) {
        const int idx = lane + k * 64;
        float4 xv[4];
        #pragma unroll
        for (int t = 0; t < 4; ++t)
            xv[t] = x4[(size_t)(t0 + t) * C4 + idx];
        #pragma unroll
        for (int e = 0; e < NE; ++e) {
            const float4 wv = gw4[e * C4 + idx];   // same addrs every block -> L2
            #pragma unroll
            for (int t = 0; t < 4; ++t) {
                acc[t][e] += xv[t].x * wv.x + xv[t].y * wv.y +
                             xv[t].z * wv.z + xv[t].w * wv.w;
            }
        }
    }

    // butterfly reduce over 64 lanes: every lane ends with full sums
    #pragma unroll
    for (int off = 32; off >= 1; off >>= 1) {
        #pragma unroll
        for (int t = 0; t < 4; ++t)
            #pragma unroll
            for (int e = 0; e < NE; ++e)
                acc[t][e] += __shfl_xor(acc[t][e], off, 64);
    }

    if (lane < 4) {
        const int t = lane;
        const int token = t0 + t;
        // static-index select (NO runtime indexing into register array!)
        float l[NE];
        #pragma unroll
        for (int e = 0; e < NE; ++e) {
            float v = acc[0][e];
            v = (t == 1) ? acc[1][e] : v;
            v = (t == 2) ? acc[2][e] : v;
            v = (t == 3) ? acc[3][e] : v;
            l[e] = v;
        }

        float m = l[0];
        #pragma unroll
        for (int e = 1; e < NE; ++e) m = fmaxf(m, l[e]);
        float p[NE];
        float s = 0.0f;
        #pragma unroll
        for (int e = 0; e < NE; ++e) { p[e] = expf(l[e] - m); s += p[e]; }
        const float inv = 1.0f / s;
        #pragma unroll
        for (int e = 0; e < NE; ++e) p[e] *= inv;

        // top-2 with ties -> lower index (matches jax.lax.top_k)
        int i0 = 0; float p0 = p[0];
        #pragma unroll
        for (int e = 1; e < NE; ++e) if (p[e] > p0) { p0 = p[e]; i0 = e; }
        int i1 = (i0 == 0) ? 1 : 0; float p1 = p[i1];
        #pragma unroll
        for (int e = 0; e < NE; ++e)
            if (e != i0 && p[e] > p1) { p1 = p[e]; i1 = e; }

        const float wsum = p0 + p1;
        out_w[2 * token]     = p0 / wsum;
        out_w[2 * token + 1] = p1 / wsum;
        out_i[2 * token]     = (float)i0;
        out_i[2 * token + 1] = (float)i1;

        #pragma unroll
        for (int e = 0; e < NE; ++e) atomicAdd(&s_psum[e], p[e]);
        atomicAdd(&s_cnt[i0], 1.0f);
        atomicAdd(&s_cnt[i1], 1.0f);
    }

    __syncthreads();
    if (tid < NE) {
        atomicAdd(&ws[tid], s_psum[tid]);
        atomicAdd(&ws[NE + tid], s_cnt[tid]);
    }
}

__global__ void finalize_kernel(const float* __restrict__ ws,
                                float* __restrict__ out) {
    float aux = 0.0f;
    #pragma unroll
    for (int e = 0; e < NE; ++e)
        aux += (ws[NE + e] * (1.0f / NTOK)) * (ws[e] * (1.0f / NTOK));
    out[4 * NTOK] = (float)NE * aux;
}

extern "C" void kernel_launch(void* const* d_in, const int* in_sizes, int n_in,
                              void* d_out, int out_size, void* d_ws, size_t ws_size,
                              hipStream_t stream) {
    const float* x  = (const float*)d_in[0];   // [4,4096,2048] f32
    const float* gw = (const float*)d_in[1];   // [8,2048] f32
    float* out = (float*)d_out;                // weights[N,2] | indices[N,2] | aux
    float* ws  = (float*)d_ws;                 // psum[8] | cnt[8]

    zero_ws_kernel<<<1, 64, 0, stream>>>(ws);
    router_kernel<<<NBLK, TPB, 0, stream>>>(x, gw, out, ws);
    finalize_kernel<<<1, 1, 0, stream>>>(ws, out);
}

// Round 5
// 64.909 us; speedup vs baseline: 2.7284x; 1.2876x over previous
//
#include <hip/hip_runtime.h>

#define NTOK 16384
#define NC 2048
#define C4 512            // float4 per row
#define NE 8
#define TPB 256           // 4 waves
#define TOK_PER_BLOCK 16  // 4 waves x 4 tokens
#define NBLK (NTOK / TOK_PER_BLOCK)   // 1024

__global__ void zero_ws_kernel(float* ws) {
    if (threadIdx.x < 2 * NE) ws[threadIdx.x] = 0.0f;
}

// VGPR-cap lore (measured R1-R4): __launch_bounds__(256,2) -> 128 VGPRs.
// (256,4)/(512,4) -> 64 VGPRs -> massive scratch spill. Keep (256,2).
// k-loop unroll MUST be limited: full unroll hoists 32 float4 loads
// (128 regs of xv) -> spills acc -> 87MB scratch traffic (R4).
__global__ __launch_bounds__(TPB, 2) void router_kernel(
    const float* __restrict__ x, const float* __restrict__ gw,
    float* __restrict__ out, float* __restrict__ ws) {
    __shared__ float s_psum[NE];
    __shared__ float s_cnt[NE];

    const int tid = threadIdx.x;
    if (tid < NE) { s_psum[tid] = 0.0f; s_cnt[tid] = 0.0f; }
    __syncthreads();

    const int wave = tid >> 6;
    const int lane = tid & 63;
    const float4* x4 = (const float4*)x;
    const float4* gw4 = (const float4*)gw;
    const int t0 = blockIdx.x * TOK_PER_BLOCK + wave * 4;   // 4 tokens per wave

    float* out_w = out;               // weights [N,2]
    float* out_i = out + 2 * NTOK;    // indices [N,2] stored as float

    float acc[4][NE];
    #pragma unroll
    for (int t = 0; t < 4; ++t)
        #pragma unroll
        for (int e = 0; e < NE; ++e) acc[t][e] = 0.0f;

    #pragma unroll 2
    for (int k = 0; k < 8; ++k) {
        const int idx = lane + k * 64;
        float4 xv[4];
        #pragma unroll
        for (int t = 0; t < 4; ++t)
            xv[t] = x4[(size_t)(t0 + t) * C4 + idx];
        #pragma unroll
        for (int e = 0; e < NE; ++e) {
            const float4 wv = gw4[e * C4 + idx];   // same addrs every block -> L1/L2
            #pragma unroll
            for (int t = 0; t < 4; ++t) {
                acc[t][e] += xv[t].x * wv.x + xv[t].y * wv.y +
                             xv[t].z * wv.z + xv[t].w * wv.w;
            }
        }
    }

    // butterfly reduce over 64 lanes: every lane ends with full sums
    #pragma unroll
    for (int off = 32; off >= 1; off >>= 1) {
        #pragma unroll
        for (int t = 0; t < 4; ++t)
            #pragma unroll
            for (int e = 0; e < NE; ++e)
                acc[t][e] += __shfl_xor(acc[t][e], off, 64);
    }

    if (lane < 4) {
        const int t = lane;
        const int token = t0 + t;
        // static-index select (NO runtime indexing into register array!)
        float l[NE];
        #pragma unroll
        for (int e = 0; e < NE; ++e) {
            float v = acc[0][e];
            v = (t == 1) ? acc[1][e] : v;
            v = (t == 2) ? acc[2][e] : v;
            v = (t == 3) ? acc[3][e] : v;
            l[e] = v;
        }

        float m = l[0];
        #pragma unroll
        for (int e = 1; e < NE; ++e) m = fmaxf(m, l[e]);
        float p[NE];
        float s = 0.0f;
        #pragma unroll
        for (int e = 0; e < NE; ++e) { p[e] = expf(l[e] - m); s += p[e]; }
        const float inv = 1.0f / s;
        #pragma unroll
        for (int e = 0; e < NE; ++e) p[e] *= inv;

        // top-2 with ties -> lower index (matches jax.lax.top_k)
        int i0 = 0; float p0 = p[0];
        #pragma unroll
        for (int e = 1; e < NE; ++e) if (p[e] > p0) { p0 = p[e]; i0 = e; }
        int i1 = (i0 == 0) ? 1 : 0; float p1 = p[i1];
        #pragma unroll
        for (int e = 0; e < NE; ++e)
            if (e != i0 && p[e] > p1) { p1 = p[e]; i1 = e; }

        const float wsum = p0 + p1;
        out_w[2 * token]     = p0 / wsum;
        out_w[2 * token + 1] = p1 / wsum;
        out_i[2 * token]     = (float)i0;
        out_i[2 * token + 1] = (float)i1;

        #pragma unroll
        for (int e = 0; e < NE; ++e) atomicAdd(&s_psum[e], p[e]);
        atomicAdd(&s_cnt[i0], 1.0f);
        atomicAdd(&s_cnt[i1], 1.0f);
    }

    __syncthreads();
    if (tid < NE) {
        atomicAdd(&ws[tid], s_psum[tid]);
        atomicAdd(&ws[NE + tid], s_cnt[tid]);
    }
}

__global__ void finalize_kernel(const float* __restrict__ ws,
                                float* __restrict__ out) {
    float aux = 0.0f;
    #pragma unroll
    for (int e = 0; e < NE; ++e)
        aux += (ws[NE + e] * (1.0f / NTOK)) * (ws[e] * (1.0f / NTOK));
    out[4 * NTOK] = (float)NE * aux;
}

extern "C" void kernel_launch(void* const* d_in, const int* in_sizes, int n_in,
                              void* d_out, int out_size, void* d_ws, size_t ws_size,
                              hipStream_t stream) {
    const float* x  = (const float*)d_in[0];   // [4,4096,2048] f32
    const float* gw = (const float*)d_in[1];   // [8,2048] f32
    float* out = (float*)d_out;                // weights[N,2] | indices[N,2] | aux
    float* ws  = (float*)d_ws;                 // psum[8] | cnt[8]

    zero_ws_kernel<<<1, 64, 0, stream>>>(ws);
    router_kernel<<<NBLK, TPB, 0, stream>>>(x, gw, out, ws);
    finalize_kernel<<<1, 1, 0, stream>>>(ws, out);
}

// Round 6
// 43.286 us; speedup vs baseline: 4.0913x; 1.4996x over previous
//
#include <hip/hip_runtime.h>

#define NTOK 16384
#define NC 2048
#define C4 512            // float4 per row
#define NE 8
#define TPB 256           // 4 waves
#define TOKW 2            // tokens per wave
#define TOK_PER_BLOCK 8   // 4 waves x 2 tokens
#define NBLK (NTOK / TOK_PER_BLOCK)   // 2048
#define NBANK 64          // aux-loss atomic banks (1 cache line each)

__global__ void zero_ws_kernel(float* ws) {
    const int tid = threadIdx.x;
    #pragma unroll
    for (int i = 0; i < 4; ++i) ws[tid + i * 256] = 0.0f;   // 1024 floats
}

// Lore (R1-R5): __launch_bounds__(256,2) -> 128 VGPR cap. Bigger min-wave
// args cap at 64 and spill. acc arrays must be SMALL (R5: acc[4][8] spilled
// by choice at VGPR=48 -> 33MB scratch = the whole bottleneck). 2 tokens/wave
// keeps live set ~60 regs.
__global__ __launch_bounds__(TPB, 2) void router_kernel(
    const float* __restrict__ x, const float* __restrict__ gw,
    float* __restrict__ out, float* __restrict__ ws) {
    __shared__ float s_psum[NE];
    __shared__ float s_cnt[NE];

    const int tid = threadIdx.x;
    if (tid < NE) { s_psum[tid] = 0.0f; s_cnt[tid] = 0.0f; }
    __syncthreads();

    const int wave = tid >> 6;
    const int lane = tid & 63;
    const float4* x4 = (const float4*)x;
    const float4* gw4 = (const float4*)gw;
    const int t0 = blockIdx.x * TOK_PER_BLOCK + wave * TOKW;

    float* out_w = out;               // weights [N,2]
    float* out_i = out + 2 * NTOK;    // indices [N,2] stored as float

    float acc0[NE], acc1[NE];
    #pragma unroll
    for (int e = 0; e < NE; ++e) { acc0[e] = 0.0f; acc1[e] = 0.0f; }

    #pragma unroll 2
    for (int k = 0; k < 8; ++k) {
        const int idx = lane + k * 64;
        const float4 xv0 = x4[(size_t)t0 * C4 + idx];
        const float4 xv1 = x4[(size_t)(t0 + 1) * C4 + idx];
        #pragma unroll
        for (int e = 0; e < NE; ++e) {
            const float4 wv = gw4[e * C4 + idx];   // same addrs every block -> L1
            acc0[e] += xv0.x * wv.x + xv0.y * wv.y + xv0.z * wv.z + xv0.w * wv.w;
            acc1[e] += xv1.x * wv.x + xv1.y * wv.y + xv1.z * wv.z + xv1.w * wv.w;
        }
    }

    // butterfly reduce over 64 lanes: every lane ends with full sums
    #pragma unroll
    for (int off = 32; off >= 1; off >>= 1) {
        #pragma unroll
        for (int e = 0; e < NE; ++e) {
            acc0[e] += __shfl_xor(acc0[e], off, 64);
            acc1[e] += __shfl_xor(acc1[e], off, 64);
        }
    }

    // every lane computes (uniform cost); lanes 0/1 own token t0/t0+1
    const int sel = lane & 1;
    float l[NE];
    #pragma unroll
    for (int e = 0; e < NE; ++e) l[e] = sel ? acc1[e] : acc0[e];

    float m = l[0];
    #pragma unroll
    for (int e = 1; e < NE; ++e) m = fmaxf(m, l[e]);
    float p[NE];
    float s = 0.0f;
    #pragma unroll
    for (int e = 0; e < NE; ++e) { p[e] = expf(l[e] - m); s += p[e]; }
    const float inv = 1.0f / s;
    #pragma unroll
    for (int e = 0; e < NE; ++e) p[e] *= inv;

    // top-2, ties -> lower index (matches jax.lax.top_k)
    int i0 = 0; float p0 = p[0];
    #pragma unroll
    for (int e = 1; e < NE; ++e) if (p[e] > p0) { p0 = p[e]; i0 = e; }
    int i1 = (i0 == 0) ? 1 : 0; float p1 = p[i1];
    #pragma unroll
    for (int e = 0; e < NE; ++e)
        if (e != i0 && p[e] > p1) { p1 = p[e]; i1 = e; }

    if (lane < TOKW) {
        const int token = t0 + lane;
        const float wsum = p0 + p1;
        out_w[2 * token]     = p0 / wsum;
        out_w[2 * token + 1] = p1 / wsum;
        out_i[2 * token]     = (float)i0;
        out_i[2 * token + 1] = (float)i1;

        #pragma unroll
        for (int e = 0; e < NE; ++e) atomicAdd(&s_psum[e], p[e]);
        atomicAdd(&s_cnt[i0], 1.0f);
        atomicAdd(&s_cnt[i1], 1.0f);
    }

    __syncthreads();
    if (tid < NE) {
        const int bank = blockIdx.x & (NBANK - 1);
        atomicAdd(&ws[bank * 16 + tid], s_psum[tid]);
        atomicAdd(&ws[bank * 16 + NE + tid], s_cnt[tid]);
    }
}

__global__ void finalize_kernel(const float* __restrict__ ws,
                                float* __restrict__ out) {
    __shared__ float red[16];
    const int tid = threadIdx.x;   // 1024 threads = NBANK*16
    if (tid < 16) red[tid] = 0.0f;
    __syncthreads();
    atomicAdd(&red[tid & 15], ws[tid]);
    __syncthreads();
    if (tid == 0) {
        float aux = 0.0f;
        #pragma unroll
        for (int e = 0; e < NE; ++e)
            aux += (red[NE + e] * (1.0f / NTOK)) * (red[e] * (1.0f / NTOK));
        out[4 * NTOK] = (float)NE * aux;
    }
}

extern "C" void kernel_launch(void* const* d_in, const int* in_sizes, int n_in,
                              void* d_out, int out_size, void* d_ws, size_t ws_size,
                              hipStream_t stream) {
    const float* x  = (const float*)d_in[0];   // [4,4096,2048] f32
    const float* gw = (const float*)d_in[1];   // [8,2048] f32
    float* out = (float*)d_out;                // weights[N,2] | indices[N,2] | aux
    float* ws  = (float*)d_ws;                 // psum/cnt in 64 banks of 16

    zero_ws_kernel<<<1, 256, 0, stream>>>(ws);
    router_kernel<<<NBLK, TPB, 0, stream>>>(x, gw, out, ws);
    finalize_kernel<<<1, 1024, 0, stream>>>(ws, out);
}